// Round 3
// baseline (669.691 us; speedup 1.0000x reference)
//
#include <hip/hip_runtime.h>
#include <stdint.h>

#define HID   128
#define OUT   4096
#define NWG   8           // persistent EP workgroups, slice = 512 cols each
#define SLICE 512         // OUT / NWG
#define NT    512
#define NXB   128         // one-shot xW1 worker blocks
#define RPX   512         // rows per xW1 block (65536 / 128)
#define NSLOT 4           // partial-buffer ring depth (deferred check needs >2)

typedef unsigned long long u64;

__device__ __forceinline__ u64 pk(uint32_t tag, float v) {
  return ((u64)tag << 32) | (u64)__float_as_uint(v);
}

// lgkm-only barrier: syncs LDS producers/consumers WITHOUT draining vmcnt, so the
// agent-scope publish store and the prefetched poll loads stay in flight across it.
// sched_barrier(0) fences stop the compiler from moving memory ops over it (rule #18).
__device__ __forceinline__ void bar_lgkm() {
  __builtin_amdgcn_sched_barrier(0);
  asm volatile("s_waitcnt lgkmcnt(0)" ::: "memory");
  __builtin_amdgcn_s_barrier();
  __builtin_amdgcn_sched_barrier(0);
}

// blockIdx < NWG: persistent EP workgroup. blockIdx >= NWG: one-shot xW1 worker.
// waves_per_eu(2,2): exactly 2 waves/SIMD (one 512-thr block/CU) -> ~256-VGPR budget,
// so w2[16][8] stays directly register-resident (no spill/remat/shuttle).
__global__ __launch_bounds__(NT, 2) __attribute__((amdgpu_waves_per_eu(2, 2)))
void k_all(
    const float* __restrict__ x,
    const float* __restrict__ W1,
    const float* __restrict__ W2,
    const float* __restrict__ b_h,
    const float* __restrict__ b_out,
    const float* __restrict__ h0,
    const float* __restrict__ o0,
    const int* __restrict__ n_iter_p,
    const float* __restrict__ eps_p,
    u64* __restrict__ pbuf,   // [NSLOT][NWG][HID] tagged h-gradient partials
    u64* __restrict__ xw1p,   // [NXB][HID] tagged xW1 partials
    float* __restrict__ out) {

  __shared__ __attribute__((aligned(16))) float red[8 * SLICE];  // 16 KB
  __shared__ __attribute__((aligned(16))) float rh_s[HID];
  __shared__ __attribute__((aligned(16))) float ro_s[SLICE];

  const int t = threadIdx.x;

  if (blockIdx.x >= NWG) {
    // ---------------- xW1 worker: partial of clip(x,0,1) @ W1 over 512 rows ------
    const int b = blockIdx.x - NWG;
    const int c4 = (t & 31) * 4;
    const int rseg = t >> 5;            // 0..15
    const int r0 = b * RPX + rseg * 32;
    float4 acc = make_float4(0.f, 0.f, 0.f, 0.f);
#pragma unroll 8
    for (int k = 0; k < 32; ++k) {
      const int r = r0 + k;
      const float rx = fminf(fmaxf(x[r], 0.f), 1.f);
      const float4 wv = *(const float4*)&W1[(size_t)r * HID + c4];
      acc.x = fmaf(rx, wv.x, acc.x); acc.y = fmaf(rx, wv.y, acc.y);
      acc.z = fmaf(rx, wv.z, acc.z); acc.w = fmaf(rx, wv.w, acc.w);
    }
    *(float4*)&red[rseg * HID + c4] = acc;
    __syncthreads();
    if (t < HID) {
      float s = 0.f;
#pragma unroll
      for (int k = 0; k < 16; k += 4)
        s += (red[k*HID + t] + red[(k+1)*HID + t]) + (red[(k+2)*HID + t] + red[(k+3)*HID + t]);
      __hip_atomic_store(&xw1p[b * HID + t], pk(1u, s),
                         __ATOMIC_RELAXED, __HIP_MEMORY_SCOPE_AGENT);
    }
    return;
  }

  // ---------------- persistent EP workgroup ---------------------------------------
  const int wg = blockIdx.x;
  const int cg = t & 63;               // lane id; owns cols cg + 64*k (k=0..7)
  const int rg = t >> 6;               // wave id; owns rows rg*16 .. rg*16+15
  const int n_iter = *n_iter_p;
  const float eps  = *eps_p;

  // ---- W2 chunk into registers: w2[r][k] = W2[rg*16+r][wg*512 + cg + 64k] ----
  float w2[16][8];
  {
    const float* wp = W2 + (size_t)(rg * 16) * OUT + wg * SLICE + cg;
#pragma unroll
    for (int r = 0; r < 16; ++r)
#pragma unroll
      for (int k = 0; k < 8; ++k)
        w2[r][k] = wp[(size_t)r * OUT + 64 * k];
  }
  // asm def: values can no longer be rematerialized from memory -> must stay in regs
#pragma unroll
  for (int r = 0; r < 16; ++r)
    asm volatile("" : "+v"(w2[r][0]), "+v"(w2[r][1]), "+v"(w2[r][2]), "+v"(w2[r][3]),
                      "+v"(w2[r][4]), "+v"(w2[r][5]), "+v"(w2[r][6]), "+v"(w2[r][7]));

  // ---- gather xW1 partials: BATCHED unconditional tagged loads, fixed-order sum ----
  float bhx = 0.f, hh = 0.f, mh = 0.f, vh = 0.f;
  if (t < HID) {
    float s = 0.f;
#pragma unroll 1
    for (int ch = 0; ch < 8; ++ch) {
      u64 v[16];
      for (;;) {
#pragma unroll
        for (int k = 0; k < 16; ++k)
          v[k] = __hip_atomic_load(&xw1p[(ch * 16 + k) * HID + t],
                                   __ATOMIC_RELAXED, __HIP_MEMORY_SCOPE_AGENT);
        uint32_t bad = 0u;
#pragma unroll
        for (int k = 0; k < 16; ++k) bad |= ((uint32_t)(v[k] >> 32)) ^ 1u;
        if (bad == 0u) break;
        __builtin_amdgcn_s_sleep(2);
      }
#pragma unroll
      for (int k = 0; k < 16; ++k) s += __uint_as_float((uint32_t)v[k]);
    }
    bhx = b_h[t] + s;
    hh  = h0[t];
    rh_s[t] = fminf(fmaxf(hh, 0.f), 1.f);
  }
  float oo = o0[wg * SLICE + t];       // one o-column per thread (SLICE == NT)
  float mo = 0.f, vo = 0.f;
  const float bo = b_out[wg * SLICE + t];
  ro_s[t] = fminf(fmaxf(oo, 0.f), 1.f);
  __syncthreads();

  // bp1/bp2 hold 0.9^it / 0.999^it at the deferred-check point (h uses step t1=it);
  // they advance before the o-update (o uses t1=it+1).
  float bp1 = 1.f, bp2 = 1.f;

  for (int it = 0; it < n_iter; ++it) {
    // ---- prefetch the partials this iteration's check will consume (tag = it,
    //      slot (it-1)&3, published by all WGs during iteration it-1). Issued HERE,
    //      waited ~1050 cyc later at the check -> MALL RT fully overlapped by PassB.
    //      Publisher lead: their publish was >= one full iteration ago. ----
    u64 pref[8];
    if (t < HID && it > 0) {
      const u64* pn = pbuf + (size_t)((it - 1) & (NSLOT - 1)) * (NWG * HID) + t;
#pragma unroll
      for (int wi = 0; wi < 8; ++wi)
        pref[wi] = __hip_atomic_load(pn + wi * HID,
                                     __ATOMIC_RELAXED, __HIP_MEMORY_SCOPE_AGENT);
    }
    asm volatile("" ::: "memory");   // pin load issue before PassB (no sinking to use)

    // ---- Pass B (registers): rows rg*16..+15, partial over this thread's 8 cols ----
    float aB[16];
    {
      float rov[8];
#pragma unroll
      for (int k = 0; k < 8; ++k) rov[k] = ro_s[cg + 64 * k];   // stride-1/lane, conflict-free
#pragma unroll
      for (int r = 0; r < 16; ++r) {
        float a = w2[r][0] * rov[0];
#pragma unroll
        for (int k = 1; k < 8; ++k) a = fmaf(w2[r][k], rov[k], a);
        aB[r] = a;
      }
    }
    // ---- in-wave fold: 64 lanes x 16 rows -> one row sum per lane quad ----
    {
#pragma unroll
      for (int r = 0; r < 8; ++r) {   // xor 32: 16 -> 8 rows
        const float keep = (cg & 32) ? aB[r + 8] : aB[r];
        const float send = (cg & 32) ? aB[r]     : aB[r + 8];
        aB[r] = keep + __shfl_xor(send, 32, 64);
      }
#pragma unroll
      for (int r = 0; r < 4; ++r) {   // xor 16: 8 -> 4
        const float keep = (cg & 16) ? aB[r + 4] : aB[r];
        const float send = (cg & 16) ? aB[r]     : aB[r + 4];
        aB[r] = keep + __shfl_xor(send, 16, 64);
      }
#pragma unroll
      for (int r = 0; r < 2; ++r) {   // xor 8: 4 -> 2
        const float keep = (cg & 8) ? aB[r + 2] : aB[r];
        const float send = (cg & 8) ? aB[r]     : aB[r + 2];
        aB[r] = keep + __shfl_xor(send, 8, 64);
      }
      {                               // xor 4: 2 -> 1
        const float keep = (cg & 4) ? aB[1] : aB[0];
        const float send = (cg & 4) ? aB[0] : aB[1];
        aB[0] = keep + __shfl_xor(send, 4, 64);
      }
      aB[0] += __shfl_xor(aB[0], 2, 64);   // duplicate folds
      aB[0] += __shfl_xor(aB[0], 1, 64);
    }

    // ---- deferred check: consume PassB(it-1) partials (prefetched at loop top).
    //      Steady state: tags already match -> zero exposed MALL latency. ----
    if (t < HID && it > 0) {
      const uint32_t tagc = (uint32_t)it;     // published at iteration it-1
      u64 v[8];
#pragma unroll
      for (int wi = 0; wi < 8; ++wi) v[wi] = pref[wi];
      uint32_t bad = 0u;
#pragma unroll
      for (int wi = 0; wi < 8; ++wi) bad |= ((uint32_t)(v[wi] >> 32)) ^ tagc;
      if (bad != 0u) {                        // prefetch was stale: retry (no sleep)
        u64* pc = pbuf + (size_t)((it - 1) & (NSLOT - 1)) * (NWG * HID);
        do {
#pragma unroll
          for (int wi = 0; wi < 8; ++wi)
            v[wi] = __hip_atomic_load(&pc[wi * HID + t],
                                      __ATOMIC_RELAXED, __HIP_MEMORY_SCOPE_AGENT);
          bad = 0u;
#pragma unroll
          for (int wi = 0; wi < 8; ++wi) bad |= ((uint32_t)(v[wi] >> 32)) ^ tagc;
        } while (bad != 0u);
      }
      const float gsum = ((__uint_as_float((uint32_t)v[0]) + __uint_as_float((uint32_t)v[1]))
                        + (__uint_as_float((uint32_t)v[2]) + __uint_as_float((uint32_t)v[3])))
                       + ((__uint_as_float((uint32_t)v[4]) + __uint_as_float((uint32_t)v[5]))
                        + (__uint_as_float((uint32_t)v[6]) + __uint_as_float((uint32_t)v[7])));
      const float c1h = 1.f / (1.f - bp1);    // bp1 = 0.9^it here (pre-advance)
      const float c2h = 1.f / (1.f - bp2);
      const float rh_old = fminf(fmaxf(hh, 0.f), 1.f);
      const float g = (hh >= 0.f && hh <= 1.f) ? (rh_old - bhx - gsum) : 0.f;
      mh = 0.9f * mh + 0.1f * g;
      vh = 0.999f * vh + 0.001f * g * g;
      hh -= eps * (mh * c1h) / (sqrtf(vh * c2h) + 1e-8f);
      rh_s[t] = fminf(fmaxf(hh, 0.f), 1.f);   // rh(it), consumed by Pass A below
    }

    // ---- publish tagged partial (row = rg*16 + cg/4, lanes cg%4==0).
    //      After the check, so the check's implicit vmcnt covers only the prefetch. ----
    if ((cg & 3) == 0) {
      u64* pp = pbuf + (size_t)(it & (NSLOT - 1)) * (NWG * HID)
                     + wg * HID + rg * 16 + (cg >> 2);
      __hip_atomic_store(pp, pk((uint32_t)(it + 1), aB[0]),
                         __ATOMIC_RELAXED, __HIP_MEMORY_SCOPE_AGENT);
    }

    bp1 *= 0.9f; bp2 *= 0.999f;               // now 0.9^(it+1): o-update factors
    const float c1 = 1.f / (1.f - bp1);
    const float c2 = 1.f / (1.f - bp2);

    bar_lgkm();   // B1: rh_s(it) visible to all waves

    // ---- Pass A: r_h @ W2 over this thread's rows ----
    {
      float aA[8] = {0.f, 0.f, 0.f, 0.f, 0.f, 0.f, 0.f, 0.f};
#pragma unroll
      for (int r = 0; r < 16; ++r) {
        const float rh = rh_s[rg * 16 + r];          // wave-uniform broadcast
#pragma unroll
        for (int k = 0; k < 8; ++k) aA[k] = fmaf(w2[r][k], rh, aA[k]);
      }
#pragma unroll
      for (int k = 0; k < 8; ++k)
        red[rg * SLICE + cg + 64 * k] = aA[k];       // stride-1/lane, conflict-free
    }
    bar_lgkm();   // B2: red visible

    // ---- g_o + Adam(o): one column (= t) per thread ----
    {
      const float s = ((red[t] + red[SLICE + t]) + (red[2*SLICE + t] + red[3*SLICE + t]))
                    + ((red[4*SLICE + t] + red[5*SLICE + t]) + (red[6*SLICE + t] + red[7*SLICE + t]));
      const float ro_old = fminf(fmaxf(oo, 0.f), 1.f);
      const float g = (oo >= 0.f && oo <= 1.f) ? (ro_old - bo - s) : 0.f;
      mo = 0.9f * mo + 0.1f * g;
      vo = 0.999f * vo + 0.001f * g * g;
      oo -= eps * (mo * c1) / (sqrtf(vo * c2) + 1e-8f);
      ro_s[t] = fminf(fmaxf(oo, 0.f), 1.f);          // ro(it+1), read next iter
    }

    bar_lgkm();   // B3: ro_s(it+1) visible for next Pass B
  }

  out[wg * SLICE + t] = oo;
}

// ---------------- launcher ----------------------------------------------------------
extern "C" void kernel_launch(void* const* d_in, const int* in_sizes, int n_in,
                              void* d_out, int out_size, void* d_ws, size_t ws_size,
                              hipStream_t stream) {
  const float* x     = (const float*)d_in[0];
  const float* W1    = (const float*)d_in[1];
  const float* W2    = (const float*)d_in[2];
  // d_in[3] = b_in (unused by the reference)
  const float* b_h   = (const float*)d_in[4];
  const float* b_out = (const float*)d_in[5];
  const float* h0    = (const float*)d_in[6];
  const float* o0    = (const float*)d_in[7];
  const int*   nit   = (const int*)d_in[8];
  const float* eps   = (const float*)d_in[9];

  u64*   pbuf = (u64*)d_ws;                         // [4][8][128] u64 = 32 KB
  u64*   xw1p = (u64*)((char*)d_ws + 32768);        // [128][128] u64 = 128 KB
  float* out  = (float*)d_out;

  // no memset needed: poisoned 0xAAAAAAAA tags never match (xw1 tag=1, iter tags=1..n)
  k_all<<<dim3(NWG + NXB), dim3(NT), 0, stream>>>(x, W1, W2, b_h, b_out, h0, o0,
                                                  nit, eps, pbuf, xw1p, out);
}

// Round 4
// 625.046 us; speedup vs baseline: 1.0714x; 1.0714x over previous
//
#include <hip/hip_runtime.h>
#include <stdint.h>

#define HID   128
#define OUT   4096
#define NWG   8           // persistent EP workgroups, slice = 512 cols each
#define SLICE 512         // OUT / NWG
#define NT    512
#define NXB   128         // one-shot xW1 worker blocks
#define RPX   512         // rows per xW1 block (65536 / 128)
#define NSLOT 4           // partial-buffer ring depth (deferred check needs >2)

typedef unsigned long long u64;

__device__ __forceinline__ u64 pk(uint32_t tag, float v) {
  return ((u64)tag << 32) | (u64)__float_as_uint(v);
}

// duplicate-fold stages via DPP quad_perm: VALU pipe, not the LDS/DS pipe.
// quad_perm {2,3,0,1} = xor2 -> ctrl 0x4E ; {1,0,3,2} = xor1 -> ctrl 0xB1.
__device__ __forceinline__ float dpp_add_xor2(float x) {
  const int y = __builtin_amdgcn_update_dpp(0, __float_as_int(x), 0x4E, 0xF, 0xF, true);
  return x + __int_as_float(y);
}
__device__ __forceinline__ float dpp_add_xor1(float x) {
  const int y = __builtin_amdgcn_update_dpp(0, __float_as_int(x), 0xB1, 0xF, 0xF, true);
  return x + __int_as_float(y);
}

// lgkm-only barrier: syncs LDS producers/consumers WITHOUT draining vmcnt, so the
// agent-scope publish store and the prefetched poll loads stay in flight across it.
// sched_barrier(0) fences stop the compiler from moving memory ops over it (rule #18).
__device__ __forceinline__ void bar_lgkm() {
  __builtin_amdgcn_sched_barrier(0);
  asm volatile("s_waitcnt lgkmcnt(0)" ::: "memory");
  __builtin_amdgcn_s_barrier();
  __builtin_amdgcn_sched_barrier(0);
}

// blockIdx < NWG: persistent EP workgroup. blockIdx >= NWG: one-shot xW1 worker.
__global__ __launch_bounds__(NT, 1) void k_all(
    const float* __restrict__ x,
    const float* __restrict__ W1,
    const float* __restrict__ W2,
    const float* __restrict__ b_h,
    const float* __restrict__ b_out,
    const float* __restrict__ h0,
    const float* __restrict__ o0,
    const int* __restrict__ n_iter_p,
    const float* __restrict__ eps_p,
    u64* __restrict__ pbuf,   // [NSLOT][NWG][HID] tagged h-gradient partials
    u64* __restrict__ xw1p,   // [NXB][HID] tagged xW1 partials
    float* __restrict__ out) {

  __shared__ __attribute__((aligned(16))) float red[8 * SLICE];  // 16 KB
  __shared__ __attribute__((aligned(16))) float rh_s[HID];
  __shared__ __attribute__((aligned(16))) float ro_s[SLICE];

  const int t = threadIdx.x;

  if (blockIdx.x >= NWG) {
    // ---------------- xW1 worker: partial of clip(x,0,1) @ W1 over 512 rows ------
    const int b = blockIdx.x - NWG;
    const int c4 = (t & 31) * 4;
    const int rseg = t >> 5;            // 0..15
    const int r0 = b * RPX + rseg * 32;
    float4 acc = make_float4(0.f, 0.f, 0.f, 0.f);
#pragma unroll 8
    for (int k = 0; k < 32; ++k) {
      const int r = r0 + k;
      const float rx = fminf(fmaxf(x[r], 0.f), 1.f);
      const float4 wv = *(const float4*)&W1[(size_t)r * HID + c4];
      acc.x = fmaf(rx, wv.x, acc.x); acc.y = fmaf(rx, wv.y, acc.y);
      acc.z = fmaf(rx, wv.z, acc.z); acc.w = fmaf(rx, wv.w, acc.w);
    }
    *(float4*)&red[rseg * HID + c4] = acc;
    __syncthreads();
    if (t < HID) {
      float s = 0.f;
#pragma unroll
      for (int k = 0; k < 16; k += 4)
        s += (red[k*HID + t] + red[(k+1)*HID + t]) + (red[(k+2)*HID + t] + red[(k+3)*HID + t]);
      __hip_atomic_store(&xw1p[b * HID + t], pk(1u, s),
                         __ATOMIC_RELAXED, __HIP_MEMORY_SCOPE_AGENT);
    }
    return;
  }

  // ---------------- persistent EP workgroup ---------------------------------------
  const int wg = blockIdx.x;
  const int cg = t & 63;               // lane id; owns cols cg + 64*k (k=0..7)
  const int rg = t >> 6;               // wave id; owns rows rg*16 .. rg*16+15
  const int n_iter = *n_iter_p;
  const float eps  = *eps_p;

  // ---- W2 chunk into registers: w2[r][k] = W2[rg*16+r][wg*512 + cg + 64k] ----
  float w2[16][8];
  {
    const float* wp = W2 + (size_t)(rg * 16) * OUT + wg * SLICE + cg;
#pragma unroll
    for (int r = 0; r < 16; ++r)
#pragma unroll
      for (int k = 0; k < 8; ++k)
        w2[r][k] = wp[(size_t)r * OUT + 64 * k];
  }
#pragma unroll
  for (int r = 0; r < 16; ++r)
    asm volatile("" : "+v"(w2[r][0]), "+v"(w2[r][1]), "+v"(w2[r][2]), "+v"(w2[r][3]),
                      "+v"(w2[r][4]), "+v"(w2[r][5]), "+v"(w2[r][6]), "+v"(w2[r][7]));

  // ---- gather xW1 partials: BATCHED unconditional tagged loads, fixed-order sum ----
  float bhx = 0.f, hh = 0.f, mh = 0.f, vh = 0.f;
  if (t < HID) {
    float s = 0.f;
#pragma unroll 1
    for (int ch = 0; ch < 8; ++ch) {
      u64 v[16];
      for (;;) {
#pragma unroll
        for (int k = 0; k < 16; ++k)
          v[k] = __hip_atomic_load(&xw1p[(ch * 16 + k) * HID + t],
                                   __ATOMIC_RELAXED, __HIP_MEMORY_SCOPE_AGENT);
        uint32_t bad = 0u;
#pragma unroll
        for (int k = 0; k < 16; ++k) bad |= ((uint32_t)(v[k] >> 32)) ^ 1u;
        if (bad == 0u) break;
        __builtin_amdgcn_s_sleep(2);
      }
#pragma unroll
      for (int k = 0; k < 16; ++k) s += __uint_as_float((uint32_t)v[k]);
    }
    bhx = b_h[t] + s;
    hh  = h0[t];
    rh_s[t] = fminf(fmaxf(hh, 0.f), 1.f);
  }
  float oo = o0[wg * SLICE + t];       // one o-column per thread (SLICE == NT)
  float mo = 0.f, vo = 0.f;
  const float bo = b_out[wg * SLICE + t];
  ro_s[t] = fminf(fmaxf(oo, 0.f), 1.f);
  __syncthreads();

  // bp1/bp2 hold 0.9^it / 0.999^it at the deferred-check point (h uses step t1=it);
  // they advance before the o-update (o uses t1=it+1).
  float bp1 = 1.f, bp2 = 1.f;
  u64 pref[8] = {0, 0, 0, 0, 0, 0, 0, 0};   // prefetched partials for next check

  for (int it = 0; it < n_iter; ++it) {
    // ---- Pass B (registers): rows rg*16..+15, partial over this thread's 8 cols ----
    float aB[16];
    {
      float rov[8];
#pragma unroll
      for (int k = 0; k < 8; ++k) rov[k] = ro_s[cg + 64 * k];   // stride-1/lane, conflict-free
#pragma unroll
      for (int r = 0; r < 16; ++r) {
        float a = w2[r][0] * rov[0];
#pragma unroll
        for (int k = 1; k < 8; ++k) a = fmaf(w2[r][k], rov[k], a);
        aB[r] = a;
      }
    }
    // ---- in-wave fold: 64 lanes x 16 rows -> one row sum per lane quad ----
    {
#pragma unroll
      for (int r = 0; r < 8; ++r) {   // xor 32: 16 -> 8 rows
        const float keep = (cg & 32) ? aB[r + 8] : aB[r];
        const float send = (cg & 32) ? aB[r]     : aB[r + 8];
        aB[r] = keep + __shfl_xor(send, 32, 64);
      }
#pragma unroll
      for (int r = 0; r < 4; ++r) {   // xor 16: 8 -> 4
        const float keep = (cg & 16) ? aB[r + 4] : aB[r];
        const float send = (cg & 16) ? aB[r]     : aB[r + 4];
        aB[r] = keep + __shfl_xor(send, 16, 64);
      }
#pragma unroll
      for (int r = 0; r < 2; ++r) {   // xor 8: 4 -> 2
        const float keep = (cg & 8) ? aB[r + 2] : aB[r];
        const float send = (cg & 8) ? aB[r]     : aB[r + 2];
        aB[r] = keep + __shfl_xor(send, 8, 64);
      }
      {                               // xor 4: 2 -> 1
        const float keep = (cg & 4) ? aB[1] : aB[0];
        const float send = (cg & 4) ? aB[0] : aB[1];
        aB[0] = keep + __shfl_xor(send, 4, 64);
      }
      aB[0] = dpp_add_xor2(aB[0]);    // duplicate folds: DPP quad_perm (VALU pipe)
      aB[0] = dpp_add_xor1(aB[0]);
    }

    // ---- publish tagged partial EARLY (row = rg*16 + cg/4, lanes cg%4==0):
    //      moved before the check so consumers get ~150 cyc more lead; at the check
    //      the store is NEWER than the pref loads, so the compiler's wait stays
    //      vmcnt(1) and never blocks on the store's MALL completion. ----
    if ((cg & 3) == 0) {
      u64* pp = pbuf + (size_t)(it & (NSLOT - 1)) * (NWG * HID)
                     + wg * HID + rg * 16 + (cg >> 2);
      __hip_atomic_store(pp, pk((uint32_t)(it + 1), aB[0]),
                         __ATOMIC_RELAXED, __HIP_MEMORY_SCOPE_AGENT);
    }

    // ---- deferred check: consume PassB(it-1) partials (prefetched last iteration).
    //      Steady state: tags already match -> zero exposed MALL latency. ----
    if (t < HID && it > 0) {
      const uint32_t tagc = (uint32_t)it;     // published at iteration it-1
      u64 v[8];
#pragma unroll
      for (int wi = 0; wi < 8; ++wi) v[wi] = pref[wi];
      uint32_t bad = 0u;
#pragma unroll
      for (int wi = 0; wi < 8; ++wi) bad |= ((uint32_t)(v[wi] >> 32)) ^ tagc;
      if (bad != 0u) {                        // prefetch was stale: retry loop
        u64* pc = pbuf + (size_t)((it - 1) & (NSLOT - 1)) * (NWG * HID);
        do {
#pragma unroll
          for (int wi = 0; wi < 8; ++wi)
            v[wi] = __hip_atomic_load(&pc[wi * HID + t],
                                      __ATOMIC_RELAXED, __HIP_MEMORY_SCOPE_AGENT);
          bad = 0u;
#pragma unroll
          for (int wi = 0; wi < 8; ++wi) bad |= ((uint32_t)(v[wi] >> 32)) ^ tagc;
          if (bad != 0u) __builtin_amdgcn_s_sleep(1);
        } while (bad != 0u);
      }
      const float gsum = ((__uint_as_float((uint32_t)v[0]) + __uint_as_float((uint32_t)v[1]))
                        + (__uint_as_float((uint32_t)v[2]) + __uint_as_float((uint32_t)v[3])))
                       + ((__uint_as_float((uint32_t)v[4]) + __uint_as_float((uint32_t)v[5]))
                        + (__uint_as_float((uint32_t)v[6]) + __uint_as_float((uint32_t)v[7])));
      const float c1h = 1.f / (1.f - bp1);    // bp1 = 0.9^it here (pre-advance)
      const float c2h = 1.f / (1.f - bp2);
      const float rh_old = fminf(fmaxf(hh, 0.f), 1.f);
      const float g = (hh >= 0.f && hh <= 1.f) ? (rh_old - bhx - gsum) : 0.f;
      mh = 0.9f * mh + 0.1f * g;
      vh = 0.999f * vh + 0.001f * g * g;
      hh -= eps * (mh * c1h) / (sqrtf(vh * c2h) + 1e-8f);
      rh_s[t] = fminf(fmaxf(hh, 0.f), 1.f);   // rh(it), consumed by Pass A below
    }

    bp1 *= 0.9f; bp2 *= 0.999f;               // now 0.9^(it+1): o-update factors
    const float c1 = 1.f / (1.f - bp1);
    const float c2 = 1.f / (1.f - bp2);

    bar_lgkm();   // B1: rh_s(it) visible to all waves

    // ---- Pass A: r_h @ W2 over this thread's rows (rh via 4x ds_read_b128) ----
    {
      float aA[8] = {0.f, 0.f, 0.f, 0.f, 0.f, 0.f, 0.f, 0.f};
      const float4* rhq = (const float4*)&rh_s[rg * 16];
#pragma unroll
      for (int rr = 0; rr < 4; ++rr) {
        const float4 rv = rhq[rr];              // 1 ds_read_b128, wave-uniform broadcast
#pragma unroll
        for (int k = 0; k < 8; ++k) {
          aA[k] = fmaf(w2[rr * 4 + 0][k], rv.x, aA[k]);
          aA[k] = fmaf(w2[rr * 4 + 1][k], rv.y, aA[k]);
          aA[k] = fmaf(w2[rr * 4 + 2][k], rv.z, aA[k]);
          aA[k] = fmaf(w2[rr * 4 + 3][k], rv.w, aA[k]);
        }
      }
#pragma unroll
      for (int k = 0; k < 8; ++k)
        red[rg * SLICE + cg + 64 * k] = aA[k];       // stride-1/lane, conflict-free
    }
    bar_lgkm();   // B2: red visible

    // ---- g_o + Adam(o): one column (= t) per thread ----
    {
      const float s = ((red[t] + red[SLICE + t]) + (red[2*SLICE + t] + red[3*SLICE + t]))
                    + ((red[4*SLICE + t] + red[5*SLICE + t]) + (red[6*SLICE + t] + red[7*SLICE + t]));
      const float ro_old = fminf(fmaxf(oo, 0.f), 1.f);
      const float g = (oo >= 0.f && oo <= 1.f) ? (ro_old - bo - s) : 0.f;
      mo = 0.9f * mo + 0.1f * g;
      vo = 0.999f * vo + 0.001f * g * g;
      oo -= eps * (mo * c1) / (sqrtf(vo * c2) + 1e-8f);
      ro_s[t] = fminf(fmaxf(oo, 0.f), 1.f);          // ro(it+1), read next iter
    }

    // ---- prefetch next check's slot (tag it+1, published this iteration).
    //      Loads stay in flight across B3 + next PassB; waited only at the check. ----
    if (t < HID && it + 1 < n_iter) {
      const u64* pn = pbuf + (size_t)(it & (NSLOT - 1)) * (NWG * HID);
#pragma unroll
      for (int wi = 0; wi < 8; ++wi)
        pref[wi] = __hip_atomic_load(&pn[wi * HID + t],
                                     __ATOMIC_RELAXED, __HIP_MEMORY_SCOPE_AGENT);
    }

    bar_lgkm();   // B3: ro_s(it+1) visible for next Pass B
  }

  out[wg * SLICE + t] = oo;
}

// ---------------- launcher ----------------------------------------------------------
extern "C" void kernel_launch(void* const* d_in, const int* in_sizes, int n_in,
                              void* d_out, int out_size, void* d_ws, size_t ws_size,
                              hipStream_t stream) {
  const float* x     = (const float*)d_in[0];
  const float* W1    = (const float*)d_in[1];
  const float* W2    = (const float*)d_in[2];
  // d_in[3] = b_in (unused by the reference)
  const float* b_h   = (const float*)d_in[4];
  const float* b_out = (const float*)d_in[5];
  const float* h0    = (const float*)d_in[6];
  const float* o0    = (const float*)d_in[7];
  const int*   nit   = (const int*)d_in[8];
  const float* eps   = (const float*)d_in[9];

  u64*   pbuf = (u64*)d_ws;                         // [4][8][128] u64 = 32 KB
  u64*   xw1p = (u64*)((char*)d_ws + 32768);        // [128][128] u64 = 128 KB
  float* out  = (float*)d_out;

  // no memset needed: poisoned 0xAAAAAAAA tags never match (xw1 tag=1, iter tags=1..n)
  k_all<<<dim3(NWG + NXB), dim3(NT), 0, stream>>>(x, W1, W2, b_h, b_out, h0, o0,
                                                  nit, eps, pbuf, xw1p, out);
}

// Round 6
// 508.791 us; speedup vs baseline: 1.3162x; 1.2285x over previous
//
#include <hip/hip_runtime.h>
#include <stdint.h>

#define HID   128
#define OUT   4096
#define NWG   8           // persistent EP workgroups, slice = 512 cols each
#define SLICE 512         // OUT / NWG
#define NT    512
#define NXB   128         // one-shot xW1 worker blocks
#define RPX   512         // rows per xW1 block (65536 / 128)
#define NSLOT 4           // partial-buffer ring depth (deferred check needs >2)

typedef unsigned long long u64;
typedef unsigned int v2u __attribute__((ext_vector_type(2)));

__device__ __forceinline__ u64 pk(uint32_t tag, float v) {
  return ((u64)tag << 32) | (u64)__float_as_uint(v);
}

// ---- VALU cross-lane primitives (guide-verified builtins only) -----------------
// permlane32_swap: exchanges vdst.hi32lanes <-> src.lo32lanes; returns both results.
// We sum the two outputs, so the {vdst,src} result-order convention cannot matter:
// sum = a[l]+a[l+32] (lanes<32, row r) / b[l-32]+b[l] (lanes>=32, row r+8).
__device__ __forceinline__ float plane32_fold(float a, float b) {
  const v2u r = __builtin_amdgcn_permlane32_swap(__float_as_uint(a), __float_as_uint(b),
                                                 false, false);
  return __uint_as_float(r.x) + __uint_as_float(r.y);
}
// DPP row_ror:8 (ctrl 0x128): within each 16-lane row, rotate by 8 == lane^8.
__device__ __forceinline__ float dpp_ror8(float x) {
  return __int_as_float(
      __builtin_amdgcn_update_dpp(0, __float_as_int(x), 0x128, 0xF, 0xF, true));
}
// quad_perm {2,3,0,1}=0x4E => xor2 ; {1,0,3,2}=0xB1 => xor1 (duplicate folds).
__device__ __forceinline__ float dpp_add_xor2(float x) {
  const int y = __builtin_amdgcn_update_dpp(0, __float_as_int(x), 0x4E, 0xF, 0xF, true);
  return x + __int_as_float(y);
}
__device__ __forceinline__ float dpp_add_xor1(float x) {
  const int y = __builtin_amdgcn_update_dpp(0, __float_as_int(x), 0xB1, 0xF, 0xF, true);
  return x + __int_as_float(y);
}

// lgkm-only barrier: syncs LDS producers/consumers WITHOUT draining vmcnt, so the
// agent-scope publish store and the prefetched poll loads stay in flight across it.
// sched_barrier(0) fences stop the compiler from moving memory ops over it (rule #18).
__device__ __forceinline__ void bar_lgkm() {
  __builtin_amdgcn_sched_barrier(0);
  asm volatile("s_waitcnt lgkmcnt(0)" ::: "memory");
  __builtin_amdgcn_s_barrier();
  __builtin_amdgcn_sched_barrier(0);
}

// blockIdx < NWG: persistent EP workgroup. blockIdx >= NWG: one-shot xW1 worker.
__global__ __launch_bounds__(NT, 1) void k_all(
    const float* __restrict__ x,
    const float* __restrict__ W1,
    const float* __restrict__ W2,
    const float* __restrict__ b_h,
    const float* __restrict__ b_out,
    const float* __restrict__ h0,
    const float* __restrict__ o0,
    const int* __restrict__ n_iter_p,
    const float* __restrict__ eps_p,
    u64* __restrict__ pbuf,   // [NSLOT][NWG][HID] tagged h-gradient partials
    u64* __restrict__ xw1p,   // [NXB][HID] tagged xW1 partials
    float* __restrict__ out) {

  __shared__ __attribute__((aligned(16))) float red[8 * SLICE];  // 16 KB
  __shared__ __attribute__((aligned(16))) float rh_s[HID];
  __shared__ __attribute__((aligned(16))) float ro_s[SLICE];

  const int t = threadIdx.x;

  if (blockIdx.x >= NWG) {
    // ---------------- xW1 worker: partial of clip(x,0,1) @ W1 over 512 rows ------
    const int b = blockIdx.x - NWG;
    const int c4 = (t & 31) * 4;
    const int rseg = t >> 5;            // 0..15
    const int r0 = b * RPX + rseg * 32;
    float4 acc = make_float4(0.f, 0.f, 0.f, 0.f);
#pragma unroll 8
    for (int k = 0; k < 32; ++k) {
      const int r = r0 + k;
      const float rx = fminf(fmaxf(x[r], 0.f), 1.f);
      const float4 wv = *(const float4*)&W1[(size_t)r * HID + c4];
      acc.x = fmaf(rx, wv.x, acc.x); acc.y = fmaf(rx, wv.y, acc.y);
      acc.z = fmaf(rx, wv.z, acc.z); acc.w = fmaf(rx, wv.w, acc.w);
    }
    *(float4*)&red[rseg * HID + c4] = acc;
    __syncthreads();
    if (t < HID) {
      float s = 0.f;
#pragma unroll
      for (int k = 0; k < 16; k += 4)
        s += (red[k*HID + t] + red[(k+1)*HID + t]) + (red[(k+2)*HID + t] + red[(k+3)*HID + t]);
      __hip_atomic_store(&xw1p[b * HID + t], pk(1u, s),
                         __ATOMIC_RELAXED, __HIP_MEMORY_SCOPE_AGENT);
    }
    return;
  }

  // ---------------- persistent EP workgroup ---------------------------------------
  const int wg = blockIdx.x;
  const int cg = t & 63;               // lane id; owns cols cg + 64*k (k=0..7)
  const int rg = t >> 6;               // wave id; owns rows rg*16 .. rg*16+15
  const int n_iter = *n_iter_p;
  const float eps  = *eps_p;

  // ---- W2 chunk into registers: w2[r][k] = W2[rg*16+r][wg*512 + cg + 64k] ----
  float w2[16][8];
  {
    const float* wp = W2 + (size_t)(rg * 16) * OUT + wg * SLICE + cg;
#pragma unroll
    for (int r = 0; r < 16; ++r)
#pragma unroll
      for (int k = 0; k < 8; ++k)
        w2[r][k] = wp[(size_t)r * OUT + 64 * k];
  }
#pragma unroll
  for (int r = 0; r < 16; ++r)
    asm volatile("" : "+v"(w2[r][0]), "+v"(w2[r][1]), "+v"(w2[r][2]), "+v"(w2[r][3]),
                      "+v"(w2[r][4]), "+v"(w2[r][5]), "+v"(w2[r][6]), "+v"(w2[r][7]));

  // ---- gather xW1 partials: BATCHED unconditional tagged loads, fixed-order sum ----
  float bhx = 0.f, hh = 0.f, mh = 0.f, vh = 0.f;
  if (t < HID) {
    float s = 0.f;
#pragma unroll 1
    for (int ch = 0; ch < 8; ++ch) {
      u64 v[16];
      for (;;) {
#pragma unroll
        for (int k = 0; k < 16; ++k)
          v[k] = __hip_atomic_load(&xw1p[(ch * 16 + k) * HID + t],
                                   __ATOMIC_RELAXED, __HIP_MEMORY_SCOPE_AGENT);
        uint32_t bad = 0u;
#pragma unroll
        for (int k = 0; k < 16; ++k) bad |= ((uint32_t)(v[k] >> 32)) ^ 1u;
        if (bad == 0u) break;
        __builtin_amdgcn_s_sleep(2);
      }
#pragma unroll
      for (int k = 0; k < 16; ++k) s += __uint_as_float((uint32_t)v[k]);
    }
    bhx = b_h[t] + s;
    hh  = h0[t];
    rh_s[t] = fminf(fmaxf(hh, 0.f), 1.f);
  }
  float oo = o0[wg * SLICE + t];       // one o-column per thread (SLICE == NT)
  float mo = 0.f, vo = 0.f;
  const float bo = b_out[wg * SLICE + t];
  ro_s[t] = fminf(fmaxf(oo, 0.f), 1.f);
  __syncthreads();

  // bp1/bp2 hold 0.9^it / 0.999^it at the deferred-check point (h uses step t1=it);
  // they advance before the o-update (o uses t1=it+1).
  float bp1 = 1.f, bp2 = 1.f;
  u64 pref[8] = {0, 0, 0, 0, 0, 0, 0, 0};   // prefetched partials for next check

  for (int it = 0; it < n_iter; ++it) {
    // ---- Pass B (registers): rows rg*16..+15, partial over this thread's 8 cols ----
    float aB[16];
    {
      float rov[8];
#pragma unroll
      for (int k = 0; k < 8; ++k) rov[k] = ro_s[cg + 64 * k];   // stride-1/lane, conflict-free
#pragma unroll
      for (int r = 0; r < 16; ++r) {
        float a = w2[r][0] * rov[0];
#pragma unroll
        for (int k = 1; k < 8; ++k) a = fmaf(w2[r][k], rov[k], a);
        aB[r] = a;
      }
    }
    // ---- in-wave fold: identical pairing tree to the all-shfl version, with the
    //      xor32 stage on permlane32_swap (VALU), xor8 on DPP row_ror (VALU),
    //      duplicate folds on quad_perm (VALU). xor16/xor4 remain shfl (DS):
    //      17 DS ops in 6 dependent stages -> 5 DS ops in 2 stages. ----
    {
#pragma unroll
      for (int r = 0; r < 8; ++r)     // xor32: 16 -> 8 rows (VALU permlane swap)
        aB[r] = plane32_fold(aB[r], aB[r + 8]);
#pragma unroll
      for (int r = 0; r < 4; ++r) {   // xor16: 8 -> 4 (DS shfl, kept)
        const float keep = (cg & 16) ? aB[r + 4] : aB[r];
        const float send = (cg & 16) ? aB[r]     : aB[r + 4];
        aB[r] = keep + __shfl_xor(send, 16, 64);
      }
#pragma unroll
      for (int r = 0; r < 2; ++r) {   // xor8: 4 -> 2 (VALU, row_ror:8 == lane^8)
        const float keep = (cg & 8) ? aB[r + 2] : aB[r];
        const float send = (cg & 8) ? aB[r]     : aB[r + 2];
        aB[r] = keep + dpp_ror8(send);
      }
      {                               // xor4: 2 -> 1 (DS shfl, kept)
        const float keep = (cg & 4) ? aB[1] : aB[0];
        const float send = (cg & 4) ? aB[0] : aB[1];
        aB[0] = keep + __shfl_xor(send, 4, 64);
      }
      aB[0] = dpp_add_xor2(aB[0]);    // duplicate folds (VALU)
      aB[0] = dpp_add_xor1(aB[0]);
    }

    // ---- deferred check: consume PassB(it-1) partials (prefetched last iteration).
    //      Steady state: tags already match -> zero exposed MALL latency. ----
    if (t < HID && it > 0) {
      const uint32_t tagc = (uint32_t)it;     // published at iteration it-1
      u64 v[8];
#pragma unroll
      for (int wi = 0; wi < 8; ++wi) v[wi] = pref[wi];
      uint32_t bad = 0u;
#pragma unroll
      for (int wi = 0; wi < 8; ++wi) bad |= ((uint32_t)(v[wi] >> 32)) ^ tagc;
      if (bad != 0u) {                        // prefetch was stale: retry loop
        u64* pc = pbuf + (size_t)((it - 1) & (NSLOT - 1)) * (NWG * HID);
        do {
#pragma unroll
          for (int wi = 0; wi < 8; ++wi)
            v[wi] = __hip_atomic_load(&pc[wi * HID + t],
                                      __ATOMIC_RELAXED, __HIP_MEMORY_SCOPE_AGENT);
          bad = 0u;
#pragma unroll
          for (int wi = 0; wi < 8; ++wi) bad |= ((uint32_t)(v[wi] >> 32)) ^ tagc;
          if (bad != 0u) __builtin_amdgcn_s_sleep(1);
        } while (bad != 0u);
      }
      const float gsum = ((__uint_as_float((uint32_t)v[0]) + __uint_as_float((uint32_t)v[1]))
                        + (__uint_as_float((uint32_t)v[2]) + __uint_as_float((uint32_t)v[3])))
                       + ((__uint_as_float((uint32_t)v[4]) + __uint_as_float((uint32_t)v[5]))
                        + (__uint_as_float((uint32_t)v[6]) + __uint_as_float((uint32_t)v[7])));
      const float c1h = 1.f / (1.f - bp1);    // bp1 = 0.9^it here (pre-advance)
      const float c2h = 1.f / (1.f - bp2);
      const float rh_old = fminf(fmaxf(hh, 0.f), 1.f);
      const float g = (hh >= 0.f && hh <= 1.f) ? (rh_old - bhx - gsum) : 0.f;
      mh = 0.9f * mh + 0.1f * g;
      vh = 0.999f * vh + 0.001f * g * g;
      hh -= eps * (mh * c1h) / (sqrtf(vh * c2h) + 1e-8f);
      rh_s[t] = fminf(fmaxf(hh, 0.f), 1.f);   // rh(it), consumed by Pass A below
    }

    // ---- publish tagged partial (row = rg*16 + cg/4, lanes cg%4==0).
    //      After the check, so the check's implicit vmcnt covers only the prefetch. ----
    if ((cg & 3) == 0) {
      u64* pp = pbuf + (size_t)(it & (NSLOT - 1)) * (NWG * HID)
                     + wg * HID + rg * 16 + (cg >> 2);
      __hip_atomic_store(pp, pk((uint32_t)(it + 1), aB[0]),
                         __ATOMIC_RELAXED, __HIP_MEMORY_SCOPE_AGENT);
    }

    bp1 *= 0.9f; bp2 *= 0.999f;               // now 0.9^(it+1): o-update factors
    const float c1 = 1.f / (1.f - bp1);
    const float c2 = 1.f / (1.f - bp2);

    bar_lgkm();   // B1: rh_s(it) visible to all waves

    // ---- Pass A: r_h @ W2 over this thread's rows ----
    {
      float aA[8] = {0.f, 0.f, 0.f, 0.f, 0.f, 0.f, 0.f, 0.f};
#pragma unroll
      for (int r = 0; r < 16; ++r) {
        const float rh = rh_s[rg * 16 + r];          // wave-uniform broadcast
#pragma unroll
        for (int k = 0; k < 8; ++k) aA[k] = fmaf(w2[r][k], rh, aA[k]);
      }
#pragma unroll
      for (int k = 0; k < 8; ++k)
        red[rg * SLICE + cg + 64 * k] = aA[k];       // stride-1/lane, conflict-free
    }
    bar_lgkm();   // B2: red visible

    // ---- g_o + Adam(o): one column (= t) per thread ----
    {
      const float s = ((red[t] + red[SLICE + t]) + (red[2*SLICE + t] + red[3*SLICE + t]))
                    + ((red[4*SLICE + t] + red[5*SLICE + t]) + (red[6*SLICE + t] + red[7*SLICE + t]));
      const float ro_old = fminf(fmaxf(oo, 0.f), 1.f);
      const float g = (oo >= 0.f && oo <= 1.f) ? (ro_old - bo - s) : 0.f;
      mo = 0.9f * mo + 0.1f * g;
      vo = 0.999f * vo + 0.001f * g * g;
      oo -= eps * (mo * c1) / (sqrtf(vo * c2) + 1e-8f);
      ro_s[t] = fminf(fmaxf(oo, 0.f), 1.f);          // ro(it+1), read next iter
    }

    // ---- prefetch next check's slot (tag it+1, published this iteration).
    //      Loads stay in flight across B3 + next PassB; waited only at the check. ----
    if (t < HID && it + 1 < n_iter) {
      const u64* pn = pbuf + (size_t)(it & (NSLOT - 1)) * (NWG * HID);
#pragma unroll
      for (int wi = 0; wi < 8; ++wi)
        pref[wi] = __hip_atomic_load(&pn[wi * HID + t],
                                     __ATOMIC_RELAXED, __HIP_MEMORY_SCOPE_AGENT);
    }

    bar_lgkm();   // B3: ro_s(it+1) visible for next Pass B
  }

  out[wg * SLICE + t] = oo;
}

// ---------------- launcher ----------------------------------------------------------
extern "C" void kernel_launch(void* const* d_in, const int* in_sizes, int n_in,
                              void* d_out, int out_size, void* d_ws, size_t ws_size,
                              hipStream_t stream) {
  const float* x     = (const float*)d_in[0];
  const float* W1    = (const float*)d_in[1];
  const float* W2    = (const float*)d_in[2];
  // d_in[3] = b_in (unused by the reference)
  const float* b_h   = (const float*)d_in[4];
  const float* b_out = (const float*)d_in[5];
  const float* h0    = (const float*)d_in[6];
  const float* o0    = (const float*)d_in[7];
  const int*   nit   = (const int*)d_in[8];
  const float* eps   = (const float*)d_in[9];

  u64*   pbuf = (u64*)d_ws;                         // [4][8][128] u64 = 32 KB
  u64*   xw1p = (u64*)((char*)d_ws + 32768);        // [128][128] u64 = 128 KB
  float* out  = (float*)d_out;

  // no memset needed: poisoned 0xAAAAAAAA tags never match (xw1 tag=1, iter tags=1..n)
  k_all<<<dim3(NWG + NXB), dim3(NT), 0, stream>>>(x, W1, W2, b_h, b_out, h0, o0,
                                                  nit, eps, pbuf, xw1p, out);
}

// Round 7
// 500.588 us; speedup vs baseline: 1.3378x; 1.0164x over previous
//
#include <hip/hip_runtime.h>
#include <stdint.h>

#define HID   128
#define OUT   4096
#define NWG   16          // persistent EP workgroups, slice = 256 cols each
#define SLICE 256         // OUT / NWG
#define NT    512
#define NXB   128         // one-shot xW1 worker blocks
#define RPX   512         // rows per xW1 block (65536 / 128)
#define NSLOT 4           // partial-buffer ring depth (deferred check needs >2)

typedef unsigned long long u64;
typedef unsigned int v2u __attribute__((ext_vector_type(2)));

__device__ __forceinline__ u64 pk(uint32_t tag, float v) {
  return ((u64)tag << 32) | (u64)__float_as_uint(v);
}

// ---- VALU cross-lane primitives (guide-verified builtins only) -----------------
// permlane32_swap: exchanges vdst.hi32lanes <-> src.lo32lanes; returns both results.
// We sum the two outputs, so the {vdst,src} result-order convention cannot matter:
// sum = a[l]+a[l+32] (lanes<32, row r) / b[l-32]+b[l] (lanes>=32, row r+8).
__device__ __forceinline__ float plane32_fold(float a, float b) {
  const v2u r = __builtin_amdgcn_permlane32_swap(__float_as_uint(a), __float_as_uint(b),
                                                 false, false);
  return __uint_as_float(r.x) + __uint_as_float(r.y);
}
// DPP row_ror:8 (ctrl 0x128): within each 16-lane row, rotate by 8 == lane^8.
__device__ __forceinline__ float dpp_ror8(float x) {
  return __int_as_float(
      __builtin_amdgcn_update_dpp(0, __float_as_int(x), 0x128, 0xF, 0xF, true));
}
// quad_perm {2,3,0,1}=0x4E => xor2 ; {1,0,3,2}=0xB1 => xor1 (final fold stages).
__device__ __forceinline__ float dpp_add_xor2(float x) {
  const int y = __builtin_amdgcn_update_dpp(0, __float_as_int(x), 0x4E, 0xF, 0xF, true);
  return x + __int_as_float(y);
}
__device__ __forceinline__ float dpp_add_xor1(float x) {
  const int y = __builtin_amdgcn_update_dpp(0, __float_as_int(x), 0xB1, 0xF, 0xF, true);
  return x + __int_as_float(y);
}

// lgkm-only barrier: syncs LDS producers/consumers WITHOUT draining vmcnt, so the
// agent-scope publish store and the prefetched poll loads stay in flight across it.
// sched_barrier(0) fences stop the compiler from moving memory ops over it (rule #18).
__device__ __forceinline__ void bar_lgkm() {
  __builtin_amdgcn_sched_barrier(0);
  asm volatile("s_waitcnt lgkmcnt(0)" ::: "memory");
  __builtin_amdgcn_s_barrier();
  __builtin_amdgcn_sched_barrier(0);
}

// blockIdx < NWG: persistent EP workgroup. blockIdx >= NWG: one-shot xW1 worker.
__global__ __launch_bounds__(NT, 1) void k_all(
    const float* __restrict__ x,
    const float* __restrict__ W1,
    const float* __restrict__ W2,
    const float* __restrict__ b_h,
    const float* __restrict__ b_out,
    const float* __restrict__ h0,
    const float* __restrict__ o0,
    const int* __restrict__ n_iter_p,
    const float* __restrict__ eps_p,
    u64* __restrict__ pbuf,   // [NSLOT][NWG][HID] tagged h-gradient partials
    u64* __restrict__ xw1p,   // [NXB][HID] tagged xW1 partials
    float* __restrict__ out) {

  __shared__ __attribute__((aligned(16))) float red[8 * SLICE];  // 8 KB (also xW1 scratch)
  __shared__ __attribute__((aligned(16))) float rh_s[HID];
  __shared__ __attribute__((aligned(16))) float ro_s[SLICE];

  const int t = threadIdx.x;

  if (blockIdx.x >= NWG) {
    // ---------------- xW1 worker: partial of clip(x,0,1) @ W1 over 512 rows ------
    const int b = blockIdx.x - NWG;
    const int c4 = (t & 31) * 4;
    const int rseg = t >> 5;            // 0..15
    const int r0 = b * RPX + rseg * 32;
    float4 acc = make_float4(0.f, 0.f, 0.f, 0.f);
#pragma unroll 8
    for (int k = 0; k < 32; ++k) {
      const int r = r0 + k;
      const float rx = fminf(fmaxf(x[r], 0.f), 1.f);
      const float4 wv = *(const float4*)&W1[(size_t)r * HID + c4];
      acc.x = fmaf(rx, wv.x, acc.x); acc.y = fmaf(rx, wv.y, acc.y);
      acc.z = fmaf(rx, wv.z, acc.z); acc.w = fmaf(rx, wv.w, acc.w);
    }
    *(float4*)&red[rseg * HID + c4] = acc;   // 16*128 = 2048 floats, fits red exactly
    __syncthreads();
    if (t < HID) {
      float s = 0.f;
#pragma unroll
      for (int k = 0; k < 16; k += 4)
        s += (red[k*HID + t] + red[(k+1)*HID + t]) + (red[(k+2)*HID + t] + red[(k+3)*HID + t]);
      __hip_atomic_store(&xw1p[b * HID + t], pk(1u, s),
                         __ATOMIC_RELAXED, __HIP_MEMORY_SCOPE_AGENT);
    }
    return;
  }

  // ---------------- persistent EP workgroup ---------------------------------------
  const int wg = blockIdx.x;
  const int cg = t & 63;               // lane id; owns cols cg + 64*k (k=0..3)
  const int rg = t >> 6;               // wave id; owns rows rg*16 .. rg*16+15
  const int n_iter = *n_iter_p;
  const float eps  = *eps_p;

  // ---- W2 chunk into registers: w2[r][k] = W2[rg*16+r][wg*256 + cg + 64k] ----
  float w2[16][4];
  {
    const float* wp = W2 + (size_t)(rg * 16) * OUT + wg * SLICE + cg;
#pragma unroll
    for (int r = 0; r < 16; ++r)
#pragma unroll
      for (int k = 0; k < 4; ++k)
        w2[r][k] = wp[(size_t)r * OUT + 64 * k];
  }
#pragma unroll
  for (int r = 0; r < 16; ++r)
    asm volatile("" : "+v"(w2[r][0]), "+v"(w2[r][1]), "+v"(w2[r][2]), "+v"(w2[r][3]));

  // ---- gather xW1 partials: BATCHED unconditional tagged loads, fixed-order sum ----
  float bhx = 0.f, hh = 0.f, mh = 0.f, vh = 0.f;
  if (t < HID) {
    float s = 0.f;
#pragma unroll 1
    for (int ch = 0; ch < 8; ++ch) {
      u64 v[16];
      for (;;) {
#pragma unroll
        for (int k = 0; k < 16; ++k)
          v[k] = __hip_atomic_load(&xw1p[(ch * 16 + k) * HID + t],
                                   __ATOMIC_RELAXED, __HIP_MEMORY_SCOPE_AGENT);
        uint32_t bad = 0u;
#pragma unroll
        for (int k = 0; k < 16; ++k) bad |= ((uint32_t)(v[k] >> 32)) ^ 1u;
        if (bad == 0u) break;
        __builtin_amdgcn_s_sleep(2);
      }
#pragma unroll
      for (int k = 0; k < 16; ++k) s += __uint_as_float((uint32_t)v[k]);
    }
    bhx = b_h[t] + s;
    hh  = h0[t];
    rh_s[t] = fminf(fmaxf(hh, 0.f), 1.f);
  }
  // o-state: one column per thread for t < SLICE only (SLICE=256 < NT)
  float oo = 0.f, mo = 0.f, vo = 0.f, bo = 0.f;
  if (t < SLICE) {
    oo = o0[wg * SLICE + t];
    bo = b_out[wg * SLICE + t];
    ro_s[t] = fminf(fmaxf(oo, 0.f), 1.f);
  }
  __syncthreads();

  // bp1/bp2 hold 0.9^it / 0.999^it at the deferred-check point (h uses step t1=it);
  // they advance before the o-update (o uses t1=it+1).
  float bp1 = 1.f, bp2 = 1.f;
  u64 pref[16];
#pragma unroll
  for (int wi = 0; wi < 16; ++wi) pref[wi] = 0;   // prefetched partials for next check

  for (int it = 0; it < n_iter; ++it) {
    // ---- Pass B (registers): rows rg*16..+15, partial over this thread's 4 cols ----
    float aB[16];
    {
      float rov[4];
#pragma unroll
      for (int k = 0; k < 4; ++k) rov[k] = ro_s[cg + 64 * k];   // stride-1/lane, conflict-free
#pragma unroll
      for (int r = 0; r < 16; ++r) {
        float a = w2[r][0] * rov[0];
#pragma unroll
        for (int k = 1; k < 4; ++k) a = fmaf(w2[r][k], rov[k], a);
        aB[r] = a;
      }
    }
    // ---- in-wave fold (same tree as R6): xor32 on permlane32_swap (VALU),
    //      xor16 shfl (DS), xor8 DPP row_ror (VALU), xor4 shfl (DS),
    //      xor2/xor1 quad_perm (VALU). Publish map: lanes cg%4==0 hold row cg>>2. ----
    {
#pragma unroll
      for (int r = 0; r < 8; ++r)     // xor32: 16 -> 8 rows (VALU permlane swap)
        aB[r] = plane32_fold(aB[r], aB[r + 8]);
#pragma unroll
      for (int r = 0; r < 4; ++r) {   // xor16: 8 -> 4 (DS shfl, kept)
        const float keep = (cg & 16) ? aB[r + 4] : aB[r];
        const float send = (cg & 16) ? aB[r]     : aB[r + 4];
        aB[r] = keep + __shfl_xor(send, 16, 64);
      }
#pragma unroll
      for (int r = 0; r < 2; ++r) {   // xor8: 4 -> 2 (VALU, row_ror:8 == lane^8)
        const float keep = (cg & 8) ? aB[r + 2] : aB[r];
        const float send = (cg & 8) ? aB[r]     : aB[r + 2];
        aB[r] = keep + dpp_ror8(send);
      }
      {                               // xor4: 2 -> 1 (DS shfl, kept)
        const float keep = (cg & 4) ? aB[1] : aB[0];
        const float send = (cg & 4) ? aB[0] : aB[1];
        aB[0] = keep + __shfl_xor(send, 4, 64);
      }
      aB[0] = dpp_add_xor2(aB[0]);    // lane bits 1,0 (VALU)
      aB[0] = dpp_add_xor1(aB[0]);
    }

    // ---- deferred check: consume PassB(it-1) partials (prefetched last iteration).
    //      Steady state: tags already match -> zero exposed MALL latency. ----
    if (t < HID && it > 0) {
      const uint32_t tagc = (uint32_t)it;     // published at iteration it-1
      u64 v[16];
#pragma unroll
      for (int wi = 0; wi < 16; ++wi) v[wi] = pref[wi];
      uint32_t bad = 0u;
#pragma unroll
      for (int wi = 0; wi < 16; ++wi) bad |= ((uint32_t)(v[wi] >> 32)) ^ tagc;
      if (bad != 0u) {                        // prefetch was stale: retry loop
        u64* pc = pbuf + (size_t)((it - 1) & (NSLOT - 1)) * (NWG * HID);
        do {
#pragma unroll
          for (int wi = 0; wi < 16; ++wi)
            v[wi] = __hip_atomic_load(&pc[wi * HID + t],
                                      __ATOMIC_RELAXED, __HIP_MEMORY_SCOPE_AGENT);
          bad = 0u;
#pragma unroll
          for (int wi = 0; wi < 16; ++wi) bad |= ((uint32_t)(v[wi] >> 32)) ^ tagc;
          if (bad != 0u) __builtin_amdgcn_s_sleep(1);
        } while (bad != 0u);
      }
      float gv[16];
#pragma unroll
      for (int wi = 0; wi < 16; ++wi) gv[wi] = __uint_as_float((uint32_t)v[wi]);
      const float gsum = (((gv[0] + gv[1]) + (gv[2] + gv[3]))
                        + ((gv[4] + gv[5]) + (gv[6] + gv[7])))
                       + (((gv[8] + gv[9]) + (gv[10] + gv[11]))
                        + ((gv[12] + gv[13]) + (gv[14] + gv[15])));
      const float c1h = 1.f / (1.f - bp1);    // bp1 = 0.9^it here (pre-advance)
      const float c2h = 1.f / (1.f - bp2);
      const float rh_old = fminf(fmaxf(hh, 0.f), 1.f);
      const float g = (hh >= 0.f && hh <= 1.f) ? (rh_old - bhx - gsum) : 0.f;
      mh = 0.9f * mh + 0.1f * g;
      vh = 0.999f * vh + 0.001f * g * g;
      hh -= eps * (mh * c1h) / (sqrtf(vh * c2h) + 1e-8f);
      rh_s[t] = fminf(fmaxf(hh, 0.f), 1.f);   // rh(it), consumed by Pass A below
    }

    // ---- publish tagged partial (row = rg*16 + cg/4, lanes cg%4==0).
    //      After the check, so the check's implicit vmcnt covers only the prefetch. ----
    if ((cg & 3) == 0) {
      u64* pp = pbuf + (size_t)(it & (NSLOT - 1)) * (NWG * HID)
                     + wg * HID + rg * 16 + (cg >> 2);
      __hip_atomic_store(pp, pk((uint32_t)(it + 1), aB[0]),
                         __ATOMIC_RELAXED, __HIP_MEMORY_SCOPE_AGENT);
    }

    bp1 *= 0.9f; bp2 *= 0.999f;               // now 0.9^(it+1): o-update factors
    const float c1 = 1.f / (1.f - bp1);
    const float c2 = 1.f / (1.f - bp2);

    bar_lgkm();   // B1: rh_s(it) visible to all waves

    // ---- Pass A: r_h @ W2 over this thread's rows ----
    {
      float aA[4] = {0.f, 0.f, 0.f, 0.f};
#pragma unroll
      for (int r = 0; r < 16; ++r) {
        const float rh = rh_s[rg * 16 + r];          // wave-uniform broadcast
#pragma unroll
        for (int k = 0; k < 4; ++k) aA[k] = fmaf(w2[r][k], rh, aA[k]);
      }
#pragma unroll
      for (int k = 0; k < 4; ++k)
        red[rg * SLICE + cg + 64 * k] = aA[k];       // stride-1/lane, conflict-free
    }
    bar_lgkm();   // B2: red visible

    // ---- g_o + Adam(o): one column (= t) per thread, t < SLICE ----
    if (t < SLICE) {
      const float s = ((red[t] + red[SLICE + t]) + (red[2*SLICE + t] + red[3*SLICE + t]))
                    + ((red[4*SLICE + t] + red[5*SLICE + t]) + (red[6*SLICE + t] + red[7*SLICE + t]));
      const float ro_old = fminf(fmaxf(oo, 0.f), 1.f);
      const float g = (oo >= 0.f && oo <= 1.f) ? (ro_old - bo - s) : 0.f;
      mo = 0.9f * mo + 0.1f * g;
      vo = 0.999f * vo + 0.001f * g * g;
      oo -= eps * (mo * c1) / (sqrtf(vo * c2) + 1e-8f);
      ro_s[t] = fminf(fmaxf(oo, 0.f), 1.f);          // ro(it+1), read next iter
    }

    // ---- prefetch next check's slot (tag it+1, published this iteration).
    //      Loads stay in flight across B3 + next PassB; waited only at the check. ----
    if (t < HID && it + 1 < n_iter) {
      const u64* pn = pbuf + (size_t)(it & (NSLOT - 1)) * (NWG * HID);
#pragma unroll
      for (int wi = 0; wi < 16; ++wi)
        pref[wi] = __hip_atomic_load(&pn[wi * HID + t],
                                     __ATOMIC_RELAXED, __HIP_MEMORY_SCOPE_AGENT);
    }

    bar_lgkm();   // B3: ro_s(it+1) visible for next Pass B
  }

  if (t < SLICE) out[wg * SLICE + t] = oo;
}

// ---------------- launcher ----------------------------------------------------------
extern "C" void kernel_launch(void* const* d_in, const int* in_sizes, int n_in,
                              void* d_out, int out_size, void* d_ws, size_t ws_size,
                              hipStream_t stream) {
  const float* x     = (const float*)d_in[0];
  const float* W1    = (const float*)d_in[1];
  const float* W2    = (const float*)d_in[2];
  // d_in[3] = b_in (unused by the reference)
  const float* b_h   = (const float*)d_in[4];
  const float* b_out = (const float*)d_in[5];
  const float* h0    = (const float*)d_in[6];
  const float* o0    = (const float*)d_in[7];
  const int*   nit   = (const int*)d_in[8];
  const float* eps   = (const float*)d_in[9];

  u64*   pbuf = (u64*)d_ws;                         // [4][16][128] u64 = 64 KB
  u64*   xw1p = (u64*)((char*)d_ws + 65536);        // [128][128] u64 = 128 KB
  float* out  = (float*)d_out;

  // no memset needed: poisoned 0xAAAAAAAA tags never match (xw1 tag=1, iter tags=1..n)
  k_all<<<dim3(NWG + NXB), dim3(NT), 0, stream>>>(x, W1, W2, b_h, b_out, h0, o0,
                                                  nit, eps, pbuf, xw1p, out);
}